// Round 14
// baseline (1543.982 us; speedup 1.0000x reference)
//
#include <hip/hip_runtime.h>
#include <hip/hip_bf16.h>

// Problem constants
#define N_ 20000
#define E_ 320000
#define G_ 128
#define H_ 4
#define C_ 64
#define D_ 256
#define ED_ 64
#define L_ 4

typedef _Float16 f16x8 __attribute__((ext_vector_type(8)));
typedef _Float16 f16x4 __attribute__((ext_vector_type(4)));
typedef _Float16 f16x2 __attribute__((ext_vector_type(2)));
typedef float f32x4 __attribute__((ext_vector_type(4)));

// ---------------- encoders ----------------
__global__ __launch_bounds__(256) void atom_enc(const float* __restrict__ x,
                                                const float* __restrict__ W,
                                                const float* __restrict__ b,
                                                _Float16* __restrict__ h16) {
    int n = blockIdx.x, t = threadIdx.x;
    float acc = b[t];
#pragma unroll
    for (int k = 0; k < 9; ++k) acc += x[n * 9 + k] * W[k * D_ + t];
    h16[(size_t)n * D_ + t] = (_Float16)acc;
}

__global__ __launch_bounds__(256) void bond_enc_perm(const float* __restrict__ ea,
                                                     const float* __restrict__ W,
                                                     const float* __restrict__ b,
                                                     const int* __restrict__ perm,
                                                     _Float16* __restrict__ e16) {
    int idx = blockIdx.x * 256 + threadIdx.x;
    if (idx >= E_ * ED_) return;
    int pos = idx >> 6, j = idx & 63;
    int orig = perm[pos];
    float acc = b[j];
#pragma unroll
    for (int k = 0; k < 3; ++k) acc += ea[orig * 3 + k] * W[k * ED_ + j];
    e16[idx] = (_Float16)acc;
}

// ---------------- CSR build (dst-sorted) ----------------
__global__ __launch_bounds__(256) void count_kernel(const int* __restrict__ dst,
                                                    int* __restrict__ deg) {
    int e = blockIdx.x * 256 + threadIdx.x;
    if (e >= E_) return;
    atomicAdd(&deg[dst[e]], 1);
}

__global__ __launch_bounds__(1024) void scan_kernel(const int* __restrict__ deg,
                                                    int* __restrict__ row_off) {
    __shared__ int part[1024];
    int t = threadIdx.x;
    const int CH = (N_ + 1023) / 1024;  // 20
    int s = 0;
    for (int i = 0; i < CH; ++i) {
        int idx = t * CH + i;
        if (idx < N_) s += deg[idx];
    }
    part[t] = s;
    __syncthreads();
    for (int off = 1; off < 1024; off <<= 1) {
        int v = (t >= off) ? part[t - off] : 0;
        __syncthreads();
        part[t] += v;
        __syncthreads();
    }
    int base = (t == 0) ? 0 : part[t - 1];
    for (int i = 0; i < CH; ++i) {
        int idx = t * CH + i;
        if (idx < N_) { row_off[idx] = base; base += deg[idx]; }
    }
    if (t == 0) row_off[N_] = part[1023];
}

__global__ __launch_bounds__(256) void fill_kernel(const int* __restrict__ src,
                                                   const int* __restrict__ dst,
                                                   const int* __restrict__ row_off,
                                                   int* __restrict__ fill,
                                                   int* __restrict__ perm,
                                                   int* __restrict__ srcp,
                                                   int* __restrict__ dstp) {
    int e = blockIdx.x * 256 + threadIdx.x;
    if (e >= E_) return;
    int d = dst[e];
    int pos = row_off[d] + atomicAdd(&fill[d], 1);
    perm[pos] = e;
    srcp[pos] = src[e];
    dstp[pos] = d;
}

// graph boundaries via binary search (batch is sorted ascending)
__global__ __launch_bounds__(256) void goff_kernel(const int* __restrict__ batch,
                                                   int* __restrict__ goff) {
    int t = threadIdx.x;
    if (t > G_) return;
    int lo = 0, hi = N_;
    while (lo < hi) { int mid = (lo + hi) >> 1; if (batch[mid] < t) lo = mid + 1; else hi = mid; }
    goff[t] = lo;
}

// ---------------- weight pre-pack: W[K][N] f32 -> WT[N][K] f16 ----------------
__global__ __launch_bounds__(256) void pack_wT(const float* __restrict__ W,
                                               _Float16* __restrict__ WT,
                                               int K, int Nn) {
    int idx = blockIdx.x * 256 + threadIdx.x;
    if (idx >= K * Nn) return;
    int n = idx / K, k = idx - n * K;
    WT[idx] = (_Float16)W[(size_t)k * Nn + n];
}

// permuted pack for edge_logits: fragment slot q = hw*64 + nt*16 + cgrp holds
// actual col n = hw*64 + cgrp*4 + nt  (K=64, Nn=256 fixed)
__global__ __launch_bounds__(256) void pack_wT_perm(const float* __restrict__ W,
                                                    _Float16* __restrict__ WTp) {
    int idx = blockIdx.x * 256 + threadIdx.x;
    if (idx >= 64 * 256) return;
    int q = idx >> 6, k = idx & 63;
    int hw = q >> 6, qq = q & 63;
    int nt = qq >> 4, cgrp = qq & 15;
    int n = hw * 64 + cgrp * 4 + nt;
    WTp[idx] = (_Float16)W[(size_t)k * 256 + n];
}

// permuted pack, K=64 Nn=64 (for eW3): slot q = nt*16+cgrp <- col cgrp*4+nt
__global__ __launch_bounds__(256) void pack_wT_perm64(const float* __restrict__ W,
                                                      _Float16* __restrict__ WTp) {
    int idx = blockIdx.x * 256 + threadIdx.x;
    if (idx >= 64 * 64) return;
    int q = idx >> 6, k = idx & 63;
    int n = (q & 15) * 4 + (q >> 4);
    WTp[idx] = (_Float16)W[(size_t)k * 64 + n];
}

// ---------------- wide MFMA f16 GEMM: 64 rows x NT*64 cols per block ---------
// A-fragment loaded ONCE, reused across NT col-tiles (A-traffic / NT).
template <int NT>
__global__ __launch_bounds__(256) void mfma_gemm16w(const _Float16* __restrict__ A16,
                                                    const _Float16* __restrict__ BT16,
                                                    const float* __restrict__ bias,
                                                    _Float16* __restrict__ C16,
                                                    int M, int K, int Nn) {
    int t = threadIdx.x;
    int w = t >> 6, l = t & 63;
    int bm = blockIdx.x * 64, bn0 = blockIdx.y * (64 * NT);
    int row0 = bm + w * 16 + (l & 15);
    int arow = row0 < M ? row0 : M - 1;
    int koff = (l >> 4) * 8;
    const _Float16* Ap = A16 + (size_t)arow * K + koff;
    f32x4 acc[NT][4] = {};
    for (int ks = 0; ks < K; ks += 32) {
        f16x8 a = *(const f16x8*)(Ap + ks);
#pragma unroll
        for (int nt = 0; nt < NT; ++nt) {
            const _Float16* Bp = BT16 + (size_t)(bn0 + nt * 64 + (l & 15)) * K + ks + koff;
            f16x8 b0 = *(const f16x8*)(Bp);
            f16x8 b1 = *(const f16x8*)(Bp + (size_t)16 * K);
            f16x8 b2 = *(const f16x8*)(Bp + (size_t)32 * K);
            f16x8 b3 = *(const f16x8*)(Bp + (size_t)48 * K);
            acc[nt][0] = __builtin_amdgcn_mfma_f32_16x16x32_f16(a, b0, acc[nt][0], 0, 0, 0);
            acc[nt][1] = __builtin_amdgcn_mfma_f32_16x16x32_f16(a, b1, acc[nt][1], 0, 0, 0);
            acc[nt][2] = __builtin_amdgcn_mfma_f32_16x16x32_f16(a, b2, acc[nt][2], 0, 0, 0);
            acc[nt][3] = __builtin_amdgcn_mfma_f32_16x16x32_f16(a, b3, acc[nt][3], 0, 0, 0);
        }
    }
#pragma unroll
    for (int nt = 0; nt < NT; ++nt) {
#pragma unroll
        for (int ct = 0; ct < 4; ++ct) {
            int col = bn0 + nt * 64 + ct * 16 + (l & 15);
            float bv = bias ? bias[col] : 0.f;
#pragma unroll
            for (int r = 0; r < 4; ++r) {
                int row = bm + w * 16 + (l >> 4) * 4 + r;
                if (row < M) C16[(size_t)row * Nn + col] = (_Float16)(acc[nt][ct][r] + bv);
            }
        }
    }
}

// ---------------- wide MFMA f16 GEMM, f32 out, bias, accum -------------------
template <int NT>
__global__ __launch_bounds__(256) void mfma_gemmw(const _Float16* __restrict__ A16,
                                                  const _Float16* __restrict__ BT16,
                                                  const float* __restrict__ bias,
                                                  float* __restrict__ C,
                                                  int M, int K, int Nn, int accum) {
    int t = threadIdx.x;
    int w = t >> 6, l = t & 63;
    int bm = blockIdx.x * 64, bn0 = blockIdx.y * (64 * NT);
    int row0 = bm + w * 16 + (l & 15);
    int arow = row0 < M ? row0 : M - 1;
    int koff = (l >> 4) * 8;
    const _Float16* Ap = A16 + (size_t)arow * K + koff;
    f32x4 acc[NT][4] = {};
    for (int ks = 0; ks < K; ks += 32) {
        f16x8 a = *(const f16x8*)(Ap + ks);
#pragma unroll
        for (int nt = 0; nt < NT; ++nt) {
            const _Float16* Bp = BT16 + (size_t)(bn0 + nt * 64 + (l & 15)) * K + ks + koff;
            f16x8 b0 = *(const f16x8*)(Bp);
            f16x8 b1 = *(const f16x8*)(Bp + (size_t)16 * K);
            f16x8 b2 = *(const f16x8*)(Bp + (size_t)32 * K);
            f16x8 b3 = *(const f16x8*)(Bp + (size_t)48 * K);
            acc[nt][0] = __builtin_amdgcn_mfma_f32_16x16x32_f16(a, b0, acc[nt][0], 0, 0, 0);
            acc[nt][1] = __builtin_amdgcn_mfma_f32_16x16x32_f16(a, b1, acc[nt][1], 0, 0, 0);
            acc[nt][2] = __builtin_amdgcn_mfma_f32_16x16x32_f16(a, b2, acc[nt][2], 0, 0, 0);
            acc[nt][3] = __builtin_amdgcn_mfma_f32_16x16x32_f16(a, b3, acc[nt][3], 0, 0, 0);
        }
    }
#pragma unroll
    for (int nt = 0; nt < NT; ++nt) {
#pragma unroll
        for (int ct = 0; ct < 4; ++ct) {
            int col = bn0 + nt * 64 + ct * 16 + (l & 15);
            float bv = bias ? bias[col] : 0.f;
#pragma unroll
            for (int r = 0; r < 4; ++r) {
                int row = bm + w * 16 + (l >> 4) * 4 + r;
                if (row < M) {
                    float v = acc[nt][ct][r] + bv;
                    if (accum) C[(size_t)row * Nn + col] += v;
                    else       C[(size_t)row * Nn + col] = v;
                }
            }
        }
    }
}

// ---------------- fused MFMA edge logits (no LDS tile, vectorized gathers) ----
__global__ __launch_bounds__(256) void edge_logits_mfma(const _Float16* __restrict__ e16,
                                                        const _Float16* __restrict__ weTp16,
                                                        const _Float16* __restrict__ xlr16,
                                                        const int* __restrict__ srcp,
                                                        const int* __restrict__ dstp,
                                                        const float* __restrict__ att,
                                                        float* __restrict__ exlog) {
    __shared__ int ssrc[64], sdst[64];
    int t = threadIdx.x;
    int w = t >> 6, l = t & 63;
    int base = blockIdx.x * 64;
    if (t < 64) { ssrc[t] = srcp[base + t]; sdst[t] = dstp[base + t]; }
    int koff = (l >> 4) * 8;
    int cgrp = l & 15;
    f16x8 bf[4][2];
#pragma unroll
    for (int nt = 0; nt < 4; ++nt) {
        const _Float16* bp = weTp16 + (size_t)(w * 64 + nt * 16 + cgrp) * 64 + koff;
        bf[nt][0] = *(const f16x8*)(bp);
        bf[nt][1] = *(const f16x8*)(bp + 32);
    }
    float4 av4 = *(const float4*)&att[w * 64 + cgrp * 4];
    float av[4] = {av4.x, av4.y, av4.z, av4.w};
    __syncthreads();
#pragma unroll
    for (int mt = 0; mt < 4; ++mt) {
        const _Float16* ap = e16 + (size_t)(base + mt * 16 + cgrp) * ED_ + koff;
        f16x8 a0 = *(const f16x8*)(ap);
        f16x8 a1 = *(const f16x8*)(ap + 32);
        f32x4 acc[4];
#pragma unroll
        for (int nt = 0; nt < 4; ++nt) {
            f32x4 z = {};
            z = __builtin_amdgcn_mfma_f32_16x16x32_f16(a0, bf[nt][0], z, 0, 0, 0);
            z = __builtin_amdgcn_mfma_f32_16x16x32_f16(a1, bf[nt][1], z, 0, 0, 0);
            acc[nt] = z;
        }
#pragma unroll
        for (int r = 0; r < 4; ++r) {
            int eidx = mt * 16 + (l >> 4) * 4 + r;
            int s = ssrc[eidx], d = sdst[eidx];
            f16x4 xlv = *(const f16x4*)&xlr16[(size_t)s * 512 + w * 64 + cgrp * 4];
            f16x4 xrv = *(const f16x4*)&xlr16[(size_t)d * 512 + 256 + w * 64 + cgrp * 4];
            float v = 0.f;
#pragma unroll
            for (int j = 0; j < 4; ++j) {
                float m = (float)xlv[j] + (float)xrv[j] + acc[j][r];
                m = fmaxf(m, 0.2f * m);   // leaky_relu, branchless
                v += m * av[j];
            }
            v += __shfl_xor(v, 1); v += __shfl_xor(v, 2);
            v += __shfl_xor(v, 4); v += __shfl_xor(v, 8);
            if (cgrp == 0) exlog[(size_t)(base + eidx) * H_ + w] = expf(v);
        }
    }
}

// ---------------- esum16: per-dst segment sum of e rows ----------------
__global__ __launch_bounds__(256) void esum_kernel(const _Float16* __restrict__ e16,
                                                   const int* __restrict__ row_off,
                                                   _Float16* __restrict__ esum16) {
    int d = blockIdx.x * 4 + (threadIdx.x >> 6);
    int lane = threadIdx.x & 63;
    if (d >= N_) return;
    int beg = row_off[d], end = row_off[d + 1];
    float s = 0.f;
    for (int i = beg; i < end; ++i) s += (float)e16[(size_t)i * ED_ + lane];
    esum16[(size_t)d * ED_ + lane] = (_Float16)s;
}

// ---------------- phase B: wave-per-dst softmax + aggregation + silu/LN ------
__global__ __launch_bounds__(256) void gat_agg4(const _Float16* __restrict__ xlr16,
                                                const _Float16* __restrict__ loopW16,
                                                const int* __restrict__ row_off,
                                                const int* __restrict__ srcp,
                                                const float* __restrict__ exlog,
                                                const float* __restrict__ att,
                                                const float* __restrict__ bias,
                                                const float* __restrict__ gs,
                                                const float* __restrict__ gb,
                                                _Float16* __restrict__ hn16) {
    int t = threadIdx.x;
    int w = t >> 6, lane = t & 63;
    int d = blockIdx.x * 4 + w;
    if (d >= N_) return;
    int beg = row_off[d], end = row_off[d + 1];
    int deg = end - beg;
    int hh = lane >> 4;
    float4 av = *(const float4*)&att[lane * 4];
    f16x4 xld_h = *(const f16x4*)&xlr16[(size_t)d * 512 + lane * 4];
    f16x4 xrd_h = *(const f16x4*)&xlr16[(size_t)d * 512 + 256 + lane * 4];
    float xld[4], xrd[4];
#pragma unroll
    for (int j = 0; j < 4; ++j) { xld[j] = (float)xld_h[j]; xrd[j] = (float)xrd_h[j]; }
    float den = 0.f;
    float out[4] = {0.f, 0.f, 0.f, 0.f};
    int i = beg;
    for (; i + 4 <= end; i += 4) {
        int s0 = srcp[i], s1 = srcp[i + 1], s2 = srcp[i + 2], s3 = srcp[i + 3];
        float ex0 = exlog[(size_t)i * H_ + hh];
        float ex1 = exlog[(size_t)(i + 1) * H_ + hh];
        float ex2 = exlog[(size_t)(i + 2) * H_ + hh];
        float ex3 = exlog[(size_t)(i + 3) * H_ + hh];
        f16x4 x0 = *(const f16x4*)&xlr16[(size_t)s0 * 512 + lane * 4];
        f16x4 x1 = *(const f16x4*)&xlr16[(size_t)s1 * 512 + lane * 4];
        f16x4 x2 = *(const f16x4*)&xlr16[(size_t)s2 * 512 + lane * 4];
        f16x4 x3 = *(const f16x4*)&xlr16[(size_t)s3 * 512 + lane * 4];
        den += (ex0 + ex1) + (ex2 + ex3);
#pragma unroll
        for (int j = 0; j < 4; ++j)
            out[j] += ex0 * (float)x0[j] + ex1 * (float)x1[j] +
                      ex2 * (float)x2[j] + ex3 * (float)x3[j];
    }
    for (; i < end; ++i) {
        int s0 = srcp[i];
        float ex0 = exlog[(size_t)i * H_ + hh];
        f16x4 x0 = *(const f16x4*)&xlr16[(size_t)s0 * 512 + lane * 4];
        den += ex0;
#pragma unroll
        for (int j = 0; j < 4; ++j) out[j] += ex0 * (float)x0[j];
    }
    // self loop
    f16x4 lw4 = *(const f16x4*)&loopW16[(size_t)d * D_ + lane * 4];
    float idg = (deg > 0) ? 1.f / (float)deg : 0.f;
    {
        float v = 0.f;
        float avv[4] = {av.x, av.y, av.z, av.w};
#pragma unroll
        for (int j = 0; j < 4; ++j) {
            float m = xld[j] + xrd[j] + (float)lw4[j] * idg;
            m = fmaxf(m, 0.2f * m);
            v += m * avv[j];
        }
        v += __shfl_xor(v, 1); v += __shfl_xor(v, 2);
        v += __shfl_xor(v, 4); v += __shfl_xor(v, 8);  // 16-lane head group
        float eself = expf(v);
        den += eself;
#pragma unroll
        for (int j = 0; j < 4; ++j) out[j] += eself * xld[j];
    }
    float inv = 1.f / (den + 1e-16f);
    float4 b4 = *(const float4*)&bias[lane * 4];
    float bv[4] = {b4.x, b4.y, b4.z, b4.w};
    float v4[4], s = 0.f;
#pragma unroll
    for (int j = 0; j < 4; ++j) {
        float v = out[j] * inv + bv[j];
        v = v / (1.f + expf(-v));
        v4[j] = v;
        s += v;
    }
#pragma unroll
    for (int o = 32; o; o >>= 1) s += __shfl_xor(s, o);
    float mu = s * (1.f / 256.f);
    float q = 0.f;
#pragma unroll
    for (int j = 0; j < 4; ++j) { float dv = v4[j] - mu; q += dv * dv; }
#pragma unroll
    for (int o = 32; o; o >>= 1) q += __shfl_xor(q, o);
    float rs = rsqrtf(q * (1.f / 256.f) + 1e-5f);
    float4 g4 = *(const float4*)&gs[lane * 4];
    float4 gb4 = *(const float4*)&gb[lane * 4];
    f16x4 o4;
    float gsv[4] = {g4.x, g4.y, g4.z, g4.w};
    float gbv[4] = {gb4.x, gb4.y, gb4.z, gb4.w};
#pragma unroll
    for (int j = 0; j < 4; ++j) o4[j] = (_Float16)((v4[j] - mu) * rs * gsv[j] + gbv[j]);
    *(f16x4*)&hn16[(size_t)d * D_ + lane * 4] = o4;
}

// ---------------- fused edge MLP (permuted eW3; vectorized gathers/stores) ----
__global__ __launch_bounds__(256) void edge_mlp_mfma(_Float16* __restrict__ e16,
                                                     const _Float16* __restrict__ ew3Tp16,
                                                     const _Float16* __restrict__ hsd16,
                                                     const int* __restrict__ srcp,
                                                     const int* __restrict__ dstp,
                                                     const float* __restrict__ eb,
                                                     const float* __restrict__ gs,
                                                     const float* __restrict__ gb) {
    int t = threadIdx.x;
    int w = t >> 6, l = t & 63;
    int bm = blockIdx.x * 64;
    int cgrp = l & 15;
    int arow = bm + w * 16 + cgrp;
    int koff = (l >> 4) * 8;
    const _Float16* Ap = e16 + (size_t)arow * ED_ + koff;
    f16x8 a0 = *(const f16x8*)(Ap);
    f16x8 a1 = *(const f16x8*)(Ap + 32);
    f32x4 acc[4];
#pragma unroll
    for (int nt = 0; nt < 4; ++nt) {
        const _Float16* bp = ew3Tp16 + (size_t)(nt * 16 + cgrp) * 64 + koff;
        f16x8 b0 = *(const f16x8*)(bp);
        f16x8 b1 = *(const f16x8*)(bp + 32);
        f32x4 z = {};
        z = __builtin_amdgcn_mfma_f32_16x16x32_f16(a0, b0, z, 0, 0, 0);
        z = __builtin_amdgcn_mfma_f32_16x16x32_f16(a1, b1, z, 0, 0, 0);
        acc[nt] = z;
    }
    f32x4 ebv = *(const f32x4*)&eb[cgrp * 4];
    f32x4 gsv = *(const f32x4*)&gs[cgrp * 4];
    f32x4 gbv = *(const f32x4*)&gb[cgrp * 4];
    int rbase = bm + w * 16 + (l >> 4) * 4;
#pragma unroll
    for (int r = 0; r < 4; ++r) {
        int row = rbase + r;
        int s = srcp[row], d = dstp[row];
        f16x4 hs = *(const f16x4*)&hsd16[(size_t)s * 128 + cgrp * 4];
        f16x4 hd = *(const f16x4*)&hsd16[(size_t)d * 128 + 64 + cgrp * 4];
        float v4[4], ss = 0.f;
#pragma unroll
        for (int nt = 0; nt < 4; ++nt) {
            float vv = acc[nt][r] + (float)hs[nt] + (float)hd[nt] + ebv[nt];
            vv = vv / (1.f + expf(-vv));
            v4[nt] = vv;
            ss += vv;
        }
        ss += __shfl_xor(ss, 1); ss += __shfl_xor(ss, 2);
        ss += __shfl_xor(ss, 4); ss += __shfl_xor(ss, 8);
        float mu = ss * (1.f / 64.f);
        float q = 0.f;
#pragma unroll
        for (int nt = 0; nt < 4; ++nt) { float dv = v4[nt] - mu; q += dv * dv; }
        q += __shfl_xor(q, 1); q += __shfl_xor(q, 2);
        q += __shfl_xor(q, 4); q += __shfl_xor(q, 8);
        float rsd = rsqrtf(q * (1.f / 64.f) + 1e-5f);
        f16x4 o4;
#pragma unroll
        for (int nt = 0; nt < 4; ++nt)
            o4[nt] = (_Float16)((v4[nt] - mu) * rsd * gsv[nt] + gbv[nt]);
        *(f16x4*)&e16[(size_t)row * ED_ + cgrp * 4] = o4;
    }
}

// ---------------- node silu + LN (final JK output; f32 + f16 outs) ----------
__global__ __launch_bounds__(256) void node_silu_ln(const float* __restrict__ inp,
                                                    const float* __restrict__ gs,
                                                    const float* __restrict__ gb,
                                                    float* __restrict__ outp,
                                                    _Float16* __restrict__ outp16) {
    int n = blockIdx.x, t = threadIdx.x;
    float v = inp[(size_t)n * D_ + t];
    v = v / (1.f + expf(-v));
    __shared__ float red[4];
    float s = v;
#pragma unroll
    for (int o = 32; o; o >>= 1) s += __shfl_xor(s, o);
    if ((t & 63) == 0) red[t >> 6] = s;
    __syncthreads();
    float mu = (red[0] + red[1] + red[2] + red[3]) * (1.f / 256.f);
    __syncthreads();
    float dv = v - mu;
    float q = dv * dv;
#pragma unroll
    for (int o = 32; o; o >>= 1) q += __shfl_xor(q, o);
    if ((t & 63) == 0) red[t >> 6] = q;
    __syncthreads();
    float var = (red[0] + red[1] + red[2] + red[3]) * (1.f / 256.f);
    float r = dv * rsqrtf(var + 1e-5f) * gs[t] + gb[t];
    outp[(size_t)n * D_ + t] = r;
    outp16[(size_t)n * D_ + t] = (_Float16)r;
}

// ---------------- gate lite: silu(hid)·gW2 reduce (no atomics) ---------------
__global__ __launch_bounds__(256) void gate_lite(const _Float16* __restrict__ hid16,
                                                 const float* __restrict__ gW2,
                                                 const float* __restrict__ gb2,
                                                 float* __restrict__ g) {
    int t = threadIdx.x;
    int w = t >> 6, lane = t & 63;
    int n = blockIdx.x * 4 + w;
    if (n >= N_) return;
    f16x2 h2 = *(const f16x2*)&hid16[(size_t)n * 128 + lane * 2];
    float h0 = (float)h2[0], h1 = (float)h2[1];
    float w0 = gW2[lane * 2], w1 = gW2[lane * 2 + 1];
    float s0 = h0 / (1.f + expf(-h0));
    float s1 = h1 / (1.f + expf(-h1));
    float v = s0 * w0 + s1 * w1;
#pragma unroll
    for (int o = 32; o; o >>= 1) v += __shfl_xor(v, o);
    if (lane == 0) g[n] = v + gb2[0];
}

// ---------------- fused per-graph pool: denom + weighted sum + head ----------
__global__ __launch_bounds__(256) void graphpool(const float* __restrict__ hfin,
                                                 const float* __restrict__ g,
                                                 const int* __restrict__ goff,
                                                 const float* __restrict__ hW,
                                                 const float* __restrict__ hb,
                                                 float* __restrict__ out) {
    int b = blockIdx.x, t = threadIdx.x;
    int w = t >> 6, lane = t & 63;
    int beg = goff[b], end = goff[b + 1];
    __shared__ float red[4];
    __shared__ float wls[256];
    float den = 0.f;
    for (int n = beg + t; n < end; n += 256) den += expf(g[n]);
#pragma unroll
    for (int o = 32; o; o >>= 1) den += __shfl_xor(den, o);
    if (lane == 0) red[w] = den;
    __syncthreads();
    float dtot = red[0] + red[1] + red[2] + red[3];
    float inv = 1.f / (dtot + 1e-16f);
    float acc = 0.f;
    for (int c0 = beg; c0 < end; c0 += 256) {
        int nn = min(256, end - c0);
        __syncthreads();
        if (t < nn) wls[t] = expf(g[c0 + t]) * inv;
        __syncthreads();
        for (int j = 0; j < nn; ++j)
            acc += wls[j] * hfin[(size_t)(c0 + j) * D_ + t];
    }
    float v = acc * hW[t];
#pragma unroll
    for (int o = 32; o; o >>= 1) v += __shfl_xor(v, o);
    __syncthreads();
    if (lane == 0) red[w] = v;
    __syncthreads();
    if (t == 0) out[b] = red[0] + red[1] + red[2] + red[3] + hb[0];
}

// ---------------- host launch ----------------
extern "C" void kernel_launch(void* const* d_in, const int* in_sizes, int n_in,
                              void* d_out, int out_size, void* d_ws, size_t ws_size,
                              hipStream_t stream) {
    const float* x     = (const float*)d_in[0];
    const int*   eidx  = (const int*)d_in[1];
    const float* eattr = (const float*)d_in[2];
    const int*   batch = (const int*)d_in[3];
    const float* atomW = (const float*)d_in[4];
    const float* atomB = (const float*)d_in[5];
    const float* bondW = (const float*)d_in[6];
    const float* bondB = (const float*)d_in[7];
    const float* Wl    = (const float*)d_in[8];
    const float* bl    = (const float*)d_in[9];
    const float* Wr    = (const float*)d_in[10];
    const float* br    = (const float*)d_in[11];
    const float* We    = (const float*)d_in[12];
    const float* att   = (const float*)d_in[13];
    const float* bias  = (const float*)d_in[14];
    const float* ln1s  = (const float*)d_in[15];
    const float* ln1b  = (const float*)d_in[16];
    const float* eW    = (const float*)d_in[17];
    const float* eb    = (const float*)d_in[18];
    const float* ln2s  = (const float*)d_in[19];
    const float* ln2b  = (const float*)d_in[20];
    const float* jkW   = (const float*)d_in[21];
    const float* jkb   = (const float*)d_in[22];
    const float* ln3s  = (const float*)d_in[23];
    const float* ln3b  = (const float*)d_in[24];
    const float* gW1   = (const float*)d_in[25];
    const float* gb1   = (const float*)d_in[26];
    const float* gW2   = (const float*)d_in[27];
    const float* gb2   = (const float*)d_in[28];
    const float* hW    = (const float*)d_in[29];
    const float* hb    = (const float*)d_in[30];

    const int* src = eidx;
    const int* dst = eidx + E_;

    // ---- workspace layout ----
    char* wp = (char*)d_ws;
    auto take = [&](size_t bytes) {
        char* p = wp;
        wp += (bytes + 255) & ~(size_t)255;
        return (void*)p;
    };
    _Float16*  e16     = (_Float16*)take((size_t)E_ * ED_ * 2);  // 40.96 MB, CSR-permuted
    _Float16*  xlr16   = (_Float16*)take((size_t)N_ * 512 * 2);  // 20.48 MB (xl|xr packed)
    float*     jkacc   = (float*)take((size_t)N_ * D_ * 4);      // 20.48 MB
    _Float16*  loopW16 = (_Float16*)take((size_t)N_ * D_ * 2);   // 10.24 MB
    float*     hfin    = (float*)take((size_t)N_ * D_ * 4);      // 20.48 MB
    _Float16*  hfin16  = (_Float16*)take((size_t)N_ * D_ * 2);   // 10.24 MB
    _Float16*  hid16   = (_Float16*)take((size_t)N_ * 128 * 2);  // 5.12 MB
    _Float16*  h16A    = (_Float16*)take((size_t)N_ * D_ * 2);   // 10.24 MB
    _Float16*  h16B    = (_Float16*)take((size_t)N_ * D_ * 2);   // 10.24 MB
    _Float16*  hsd16   = (_Float16*)take((size_t)N_ * 128 * 2);  // 5.12 MB (hsW|hdW packed)
    float*     exlog   = (float*)take((size_t)E_ * H_ * 4);      // 5.12 MB
    _Float16*  esum16  = (_Float16*)take((size_t)N_ * ED_ * 2);  // 2.56 MB
    _Float16*  wlrT16  = (_Float16*)take((size_t)L_ * 512 * D_ * 2);
    _Float16*  weT16   = (_Float16*)take((size_t)L_ * ED_ * D_ * 2);
    _Float16*  weTp16  = (_Float16*)take((size_t)L_ * ED_ * D_ * 2);  // permuted (edge_logits)
    _Float16*  ewsdT16 = (_Float16*)take((size_t)L_ * 128 * D_ * 2);
    _Float16*  ew3Tp16 = (_Float16*)take((size_t)L_ * ED_ * ED_ * 2); // permuted (edge_mlp)
    _Float16*  jkwT16  = (_Float16*)take((size_t)L_ * D_ * D_ * 2);
    _Float16*  g1T16   = (_Float16*)take((size_t)D_ * 128 * 2);
    float*     blr     = (float*)take((size_t)L_ * 512 * 4);
    int*   deg_i   = (int*)take((size_t)N_ * 4);
    int*   fill    = (int*)take((size_t)N_ * 4);
    int*   row_off = (int*)take((size_t)(N_ + 1) * 4);
    int*   goff    = (int*)take((size_t)(G_ + 1) * 4);
    int*   perm    = (int*)take((size_t)E_ * 4);
    int*   srcp    = (int*)take((size_t)E_ * 4);
    int*   dstp    = (int*)take((size_t)E_ * 4);
    float* g       = (float*)take((size_t)N_ * 4);

    // ---- weight pre-pack (f32 -> transposed f16) ----
    auto pack = [&](const float* W, _Float16* WT, int K, int Nn) {
        pack_wT<<<(K * Nn + 255) / 256, 256, 0, stream>>>(W, WT, K, Nn);
    };
    for (int l = 0; l < L_; ++l) {
        pack(Wl + (size_t)l * D_ * D_, wlrT16 + (size_t)l * 512 * D_, D_, D_);
        pack(Wr + (size_t)l * D_ * D_, wlrT16 + (size_t)l * 512 * D_ + (size_t)D_ * D_, D_, D_);
        pack(We + (size_t)l * ED_ * D_, weT16 + (size_t)l * ED_ * D_, ED_, D_);
        pack_wT_perm<<<(64 * 256 + 255) / 256, 256, 0, stream>>>(
            We + (size_t)l * ED_ * D_, weTp16 + (size_t)l * ED_ * D_);
        const float* eW_l = eW + (size_t)l * (2 * D_ + ED_) * ED_;
        pack(eW_l,                        ewsdT16 + (size_t)l * 128 * D_, D_, ED_);
        pack(eW_l + (size_t)D_ * ED_,     ewsdT16 + (size_t)l * 128 * D_ + (size_t)ED_ * D_, D_, ED_);
        pack_wT_perm64<<<(64 * 64 + 255) / 256, 256, 0, stream>>>(
            eW_l + (size_t)2 * D_ * ED_, ew3Tp16 + (size_t)l * ED_ * ED_);
        pack(jkW + (size_t)l * D_ * D_,   jkwT16 + (size_t)l * D_ * D_, D_, D_);
        hipMemcpyAsync(blr + (size_t)l * 512,       bl + (size_t)l * D_, D_ * 4,
                       hipMemcpyDeviceToDevice, stream);
        hipMemcpyAsync(blr + (size_t)l * 512 + D_,  br + (size_t)l * D_, D_ * 4,
                       hipMemcpyDeviceToDevice, stream);
    }
    pack(gW1, g1T16, D_, 128);

    // ---- CSR build + graph boundaries ----
    hipMemsetAsync(deg_i, 0, (size_t)N_ * 4, stream);
    hipMemsetAsync(fill, 0, (size_t)N_ * 4, stream);
    count_kernel<<<(E_ + 255) / 256, 256, 0, stream>>>(dst, deg_i);
    scan_kernel<<<1, 1024, 0, stream>>>(deg_i, row_off);
    fill_kernel<<<(E_ + 255) / 256, 256, 0, stream>>>(src, dst, row_off, fill,
                                                      perm, srcp, dstp);
    goff_kernel<<<1, 256, 0, stream>>>(batch, goff);

    // encoders
    atom_enc<<<N_, 256, 0, stream>>>(x, atomW, atomB, h16A);
    bond_enc_perm<<<(E_ * ED_ + 255) / 256, 256, 0, stream>>>(eattr, bondW, bondB,
                                                              perm, e16);

    const int MB = (N_ + 63) / 64;  // 313
    const _Float16* h16_prev = h16A;
    for (int l = 0; l < L_; ++l) {
        const float* att_l = att + (size_t)l * H_ * C_;
        const float* bias_l = bias + (size_t)l * D_;
        const float* ln1s_l = ln1s + (size_t)l * D_;
        const float* ln1b_l = ln1b + (size_t)l * D_;
        const float* eb_l = eb + (size_t)l * ED_;
        const float* ln2s_l = ln2s + (size_t)l * ED_;
        const float* ln2b_l = ln2b + (size_t)l * ED_;
        const _Float16* weT_l = weT16 + (size_t)l * ED_ * D_;
        _Float16* hn16_l = (l & 1) ? h16A : h16B;

        // xl|xr projection: wide GEMM (A read once per 256-col tile)
        mfma_gemm16w<4><<<dim3(MB, 2), 256, 0, stream>>>(h16_prev,
                                                         wlrT16 + (size_t)l * 512 * D_,
                                                         blr + (size_t)l * 512,
                                                         xlr16, N_, D_, 512);

        // self-loop: esum16 @ We -> loopW16 (f16, wide)
        esum_kernel<<<(N_ + 3) / 4, 256, 0, stream>>>(e16, row_off, esum16);
        mfma_gemm16w<4><<<dim3(MB, 1), 256, 0, stream>>>(esum16, weT_l, nullptr,
                                                         loopW16, N_, ED_, D_);

        // phase A: fused MFMA edge logits (no-LDS, permuted weights)
        edge_logits_mfma<<<E_ / 64, 256, 0, stream>>>(e16,
                                                      weTp16 + (size_t)l * ED_ * D_,
                                                      xlr16, srcp, dstp, att_l, exlog);

        // phase B: wave-per-dst softmax + aggregation + silu/LN -> hn16
        gat_agg4<<<(N_ + 3) / 4, 256, 0, stream>>>(xlr16, loopW16, row_off, srcp,
                                                   exlog, att_l, bias_l,
                                                   ln1s_l, ln1b_l, hn16_l);

        // edge MLP: hsd16 = hn@[eWs|eWd] (wide), then fused MFMA+LN in-place
        mfma_gemm16w<2><<<dim3(MB, 1), 256, 0, stream>>>(hn16_l,
                                                         ewsdT16 + (size_t)l * 128 * D_,
                                                         nullptr, hsd16, N_, D_, 128);
        edge_mlp_mfma<<<E_ / 64, 256, 0, stream>>>(e16, ew3Tp16 + (size_t)l * ED_ * ED_,
                                                   hsd16, srcp, dstp,
                                                   eb_l, ln2s_l, ln2b_l);

        // incremental JK: jkacc (+)= hn @ jkW_l (f32 accum, wide)
        mfma_gemmw<4><<<dim3(MB, 1), 256, 0, stream>>>(hn16_l, jkwT16 + (size_t)l * D_ * D_,
                                                       (l == 0) ? jkb : nullptr,
                                                       jkacc, N_, D_, D_, (l == 0) ? 0 : 1);

        h16_prev = hn16_l;
    }

    node_silu_ln<<<N_, 256, 0, stream>>>(jkacc, ln3s, ln3b, hfin, hfin16);

    // gate MLP (MFMA, f16 hid, wide) -> per-node logit -> fused pool + head
    mfma_gemm16w<2><<<dim3(MB, 1), 256, 0, stream>>>(hfin16, g1T16, gb1, hid16, N_, D_, 128);
    gate_lite<<<(N_ + 3) / 4, 256, 0, stream>>>(hid16, gW2, gb2, g);
    graphpool<<<G_, 256, 0, stream>>>(hfin, g, goff, hW, hb, (float*)d_out);
}

// Round 15
// 1356.496 us; speedup vs baseline: 1.1382x; 1.1382x over previous
//
#include <hip/hip_runtime.h>
#include <hip/hip_bf16.h>

// Problem constants
#define N_ 20000
#define E_ 320000
#define G_ 128
#define H_ 4
#define C_ 64
#define D_ 256
#define ED_ 64
#define L_ 4

typedef _Float16 f16x8 __attribute__((ext_vector_type(8)));
typedef _Float16 f16x4 __attribute__((ext_vector_type(4)));
typedef _Float16 f16x2 __attribute__((ext_vector_type(2)));
typedef float f32x4 __attribute__((ext_vector_type(4)));

// ---------------- encoders ----------------
__global__ __launch_bounds__(256) void atom_enc(const float* __restrict__ x,
                                                const float* __restrict__ W,
                                                const float* __restrict__ b,
                                                _Float16* __restrict__ h16) {
    int n = blockIdx.x, t = threadIdx.x;
    float acc = b[t];
#pragma unroll
    for (int k = 0; k < 9; ++k) acc += x[n * 9 + k] * W[k * D_ + t];
    h16[(size_t)n * D_ + t] = (_Float16)acc;
}

__global__ __launch_bounds__(256) void bond_enc_perm(const float* __restrict__ ea,
                                                     const float* __restrict__ W,
                                                     const float* __restrict__ b,
                                                     const int* __restrict__ perm,
                                                     _Float16* __restrict__ e16) {
    int idx = blockIdx.x * 256 + threadIdx.x;
    if (idx >= E_ * ED_) return;
    int pos = idx >> 6, j = idx & 63;
    int orig = perm[pos];
    float acc = b[j];
#pragma unroll
    for (int k = 0; k < 3; ++k) acc += ea[orig * 3 + k] * W[k * ED_ + j];
    e16[idx] = (_Float16)acc;
}

// ---------------- CSR build (dst-sorted) ----------------
__global__ __launch_bounds__(256) void count_kernel(const int* __restrict__ dst,
                                                    int* __restrict__ deg) {
    int e = blockIdx.x * 256 + threadIdx.x;
    if (e >= E_) return;
    atomicAdd(&deg[dst[e]], 1);
}

__global__ __launch_bounds__(1024) void scan_kernel(const int* __restrict__ deg,
                                                    int* __restrict__ row_off) {
    __shared__ int part[1024];
    int t = threadIdx.x;
    const int CH = (N_ + 1023) / 1024;  // 20
    int s = 0;
    for (int i = 0; i < CH; ++i) {
        int idx = t * CH + i;
        if (idx < N_) s += deg[idx];
    }
    part[t] = s;
    __syncthreads();
    for (int off = 1; off < 1024; off <<= 1) {
        int v = (t >= off) ? part[t - off] : 0;
        __syncthreads();
        part[t] += v;
        __syncthreads();
    }
    int base = (t == 0) ? 0 : part[t - 1];
    for (int i = 0; i < CH; ++i) {
        int idx = t * CH + i;
        if (idx < N_) { row_off[idx] = base; base += deg[idx]; }
    }
    if (t == 0) row_off[N_] = part[1023];
}

__global__ __launch_bounds__(256) void fill_kernel(const int* __restrict__ src,
                                                   const int* __restrict__ dst,
                                                   const int* __restrict__ row_off,
                                                   int* __restrict__ fill,
                                                   int* __restrict__ perm,
                                                   int* __restrict__ srcp,
                                                   int* __restrict__ dstp) {
    int e = blockIdx.x * 256 + threadIdx.x;
    if (e >= E_) return;
    int d = dst[e];
    int pos = row_off[d] + atomicAdd(&fill[d], 1);
    perm[pos] = e;
    srcp[pos] = src[e];
    dstp[pos] = d;
}

// graph boundaries via binary search (batch is sorted ascending)
__global__ __launch_bounds__(256) void goff_kernel(const int* __restrict__ batch,
                                                   int* __restrict__ goff) {
    int t = threadIdx.x;
    if (t > G_) return;
    int lo = 0, hi = N_;
    while (lo < hi) { int mid = (lo + hi) >> 1; if (batch[mid] < t) lo = mid + 1; else hi = mid; }
    goff[t] = lo;
}

// ---------------- weight pre-pack: W[K][N] f32 -> WT[N][K] f16 ----------------
__global__ __launch_bounds__(256) void pack_wT(const float* __restrict__ W,
                                               _Float16* __restrict__ WT,
                                               int K, int Nn) {
    int idx = blockIdx.x * 256 + threadIdx.x;
    if (idx >= K * Nn) return;
    int n = idx / K, k = idx - n * K;
    WT[idx] = (_Float16)W[(size_t)k * Nn + n];
}

// permuted pack for edge_logits: fragment slot q = hw*64 + nt*16 + cgrp holds
// actual col n = hw*64 + cgrp*4 + nt  (K=64, Nn=256 fixed)
__global__ __launch_bounds__(256) void pack_wT_perm(const float* __restrict__ W,
                                                    _Float16* __restrict__ WTp) {
    int idx = blockIdx.x * 256 + threadIdx.x;
    if (idx >= 64 * 256) return;
    int q = idx >> 6, k = idx & 63;
    int hw = q >> 6, qq = q & 63;
    int nt = qq >> 4, cgrp = qq & 15;
    int n = hw * 64 + cgrp * 4 + nt;
    WTp[idx] = (_Float16)W[(size_t)k * 256 + n];
}

// permuted pack, K=64 Nn=64 (for eW3): slot q = nt*16+cgrp <- col cgrp*4+nt
__global__ __launch_bounds__(256) void pack_wT_perm64(const float* __restrict__ W,
                                                      _Float16* __restrict__ WTp) {
    int idx = blockIdx.x * 256 + threadIdx.x;
    if (idx >= 64 * 64) return;
    int q = idx >> 6, k = idx & 63;
    int n = (q & 15) * 4 + (q >> 4);
    WTp[idx] = (_Float16)W[(size_t)k * 64 + n];
}

// ---------------- MFMA f16 GEMM (f32 out, bias, accum) ----------------
__global__ __launch_bounds__(256) void mfma_gemm(const _Float16* __restrict__ A16,
                                                 const _Float16* __restrict__ BT16,
                                                 const float* __restrict__ bias,
                                                 float* __restrict__ C,
                                                 int M, int K, int Nn, int accum) {
    int t = threadIdx.x;
    int w = t >> 6, l = t & 63;
    int bm = blockIdx.x * 64, bn = blockIdx.y * 64;
    int row0 = bm + w * 16 + (l & 15);
    int arow = row0 < M ? row0 : M - 1;
    int koff = (l >> 4) * 8;
    const _Float16* Ap = A16 + (size_t)arow * K + koff;
    f32x4 acc0 = {}, acc1 = {}, acc2 = {}, acc3 = {};
    for (int ks = 0; ks < K; ks += 32) {
        f16x8 a = *(const f16x8*)(Ap + ks);
        const _Float16* Bp = BT16 + (size_t)(bn + (l & 15)) * K + ks + koff;
        f16x8 b0 = *(const f16x8*)(Bp);
        f16x8 b1 = *(const f16x8*)(Bp + (size_t)16 * K);
        f16x8 b2 = *(const f16x8*)(Bp + (size_t)32 * K);
        f16x8 b3 = *(const f16x8*)(Bp + (size_t)48 * K);
        acc0 = __builtin_amdgcn_mfma_f32_16x16x32_f16(a, b0, acc0, 0, 0, 0);
        acc1 = __builtin_amdgcn_mfma_f32_16x16x32_f16(a, b1, acc1, 0, 0, 0);
        acc2 = __builtin_amdgcn_mfma_f32_16x16x32_f16(a, b2, acc2, 0, 0, 0);
        acc3 = __builtin_amdgcn_mfma_f32_16x16x32_f16(a, b3, acc3, 0, 0, 0);
    }
    f32x4 accs[4] = {acc0, acc1, acc2, acc3};
#pragma unroll
    for (int ct = 0; ct < 4; ++ct) {
        int col = bn + ct * 16 + (l & 15);
#pragma unroll
        for (int r = 0; r < 4; ++r) {
            int row = bm + w * 16 + (l >> 4) * 4 + r;
            if (row < M) {
                float v = accs[ct][r] + (bias ? bias[col] : 0.f);
                if (accum) C[(size_t)row * Nn + col] += v;
                else       C[(size_t)row * Nn + col] = v;
            }
        }
    }
}

// ---------------- MFMA f16 GEMM, f16 out, optional bias ----------------
__global__ __launch_bounds__(256) void mfma_gemm16(const _Float16* __restrict__ A16,
                                                   const _Float16* __restrict__ BT16,
                                                   const float* __restrict__ bias,
                                                   _Float16* __restrict__ C16,
                                                   int M, int K, int Nn) {
    int t = threadIdx.x;
    int w = t >> 6, l = t & 63;
    int bm = blockIdx.x * 64, bn = blockIdx.y * 64;
    int row0 = bm + w * 16 + (l & 15);
    int arow = row0 < M ? row0 : M - 1;
    int koff = (l >> 4) * 8;
    const _Float16* Ap = A16 + (size_t)arow * K + koff;
    f32x4 acc0 = {}, acc1 = {}, acc2 = {}, acc3 = {};
    for (int ks = 0; ks < K; ks += 32) {
        f16x8 a = *(const f16x8*)(Ap + ks);
        const _Float16* Bp = BT16 + (size_t)(bn + (l & 15)) * K + ks + koff;
        f16x8 b0 = *(const f16x8*)(Bp);
        f16x8 b1 = *(const f16x8*)(Bp + (size_t)16 * K);
        f16x8 b2 = *(const f16x8*)(Bp + (size_t)32 * K);
        f16x8 b3 = *(const f16x8*)(Bp + (size_t)48 * K);
        acc0 = __builtin_amdgcn_mfma_f32_16x16x32_f16(a, b0, acc0, 0, 0, 0);
        acc1 = __builtin_amdgcn_mfma_f32_16x16x32_f16(a, b1, acc1, 0, 0, 0);
        acc2 = __builtin_amdgcn_mfma_f32_16x16x32_f16(a, b2, acc2, 0, 0, 0);
        acc3 = __builtin_amdgcn_mfma_f32_16x16x32_f16(a, b3, acc3, 0, 0, 0);
    }
    f32x4 accs[4] = {acc0, acc1, acc2, acc3};
#pragma unroll
    for (int ct = 0; ct < 4; ++ct) {
        int col = bn + ct * 16 + (l & 15);
        float bv = bias ? bias[col] : 0.f;
#pragma unroll
        for (int r = 0; r < 4; ++r) {
            int row = bm + w * 16 + (l >> 4) * 4 + r;
            if (row < M) C16[(size_t)row * Nn + col] = (_Float16)(accs[ct][r] + bv);
        }
    }
}

// ---------------- fused MFMA edge logits (no LDS tile, vectorized gathers) ----
__global__ __launch_bounds__(256) void edge_logits_mfma(const _Float16* __restrict__ e16,
                                                        const _Float16* __restrict__ weTp16,
                                                        const _Float16* __restrict__ xlr16,
                                                        const int* __restrict__ srcp,
                                                        const int* __restrict__ dstp,
                                                        const float* __restrict__ att,
                                                        float* __restrict__ exlog) {
    __shared__ int ssrc[64], sdst[64];
    int t = threadIdx.x;
    int w = t >> 6, l = t & 63;
    int base = blockIdx.x * 64;
    if (t < 64) { ssrc[t] = srcp[base + t]; sdst[t] = dstp[base + t]; }
    int koff = (l >> 4) * 8;
    int cgrp = l & 15;
    f16x8 bf[4][2];
#pragma unroll
    for (int nt = 0; nt < 4; ++nt) {
        const _Float16* bp = weTp16 + (size_t)(w * 64 + nt * 16 + cgrp) * 64 + koff;
        bf[nt][0] = *(const f16x8*)(bp);
        bf[nt][1] = *(const f16x8*)(bp + 32);
    }
    float4 av4 = *(const float4*)&att[w * 64 + cgrp * 4];
    float av[4] = {av4.x, av4.y, av4.z, av4.w};
    __syncthreads();
#pragma unroll
    for (int mt = 0; mt < 4; ++mt) {
        const _Float16* ap = e16 + (size_t)(base + mt * 16 + cgrp) * ED_ + koff;
        f16x8 a0 = *(const f16x8*)(ap);
        f16x8 a1 = *(const f16x8*)(ap + 32);
        f32x4 acc[4];
#pragma unroll
        for (int nt = 0; nt < 4; ++nt) {
            f32x4 z = {};
            z = __builtin_amdgcn_mfma_f32_16x16x32_f16(a0, bf[nt][0], z, 0, 0, 0);
            z = __builtin_amdgcn_mfma_f32_16x16x32_f16(a1, bf[nt][1], z, 0, 0, 0);
            acc[nt] = z;
        }
#pragma unroll
        for (int r = 0; r < 4; ++r) {
            int eidx = mt * 16 + (l >> 4) * 4 + r;
            int s = ssrc[eidx], d = sdst[eidx];
            f16x4 xlv = *(const f16x4*)&xlr16[(size_t)s * 512 + w * 64 + cgrp * 4];
            f16x4 xrv = *(const f16x4*)&xlr16[(size_t)d * 512 + 256 + w * 64 + cgrp * 4];
            float v = 0.f;
#pragma unroll
            for (int j = 0; j < 4; ++j) {
                float m = (float)xlv[j] + (float)xrv[j] + acc[j][r];
                m = fmaxf(m, 0.2f * m);   // leaky_relu, branchless
                v += m * av[j];
            }
            v += __shfl_xor(v, 1); v += __shfl_xor(v, 2);
            v += __shfl_xor(v, 4); v += __shfl_xor(v, 8);
            if (cgrp == 0) exlog[(size_t)(base + eidx) * H_ + w] = expf(v);
        }
    }
}

// ---------------- esum16: per-dst segment sum of e rows ----------------
__global__ __launch_bounds__(256) void esum_kernel(const _Float16* __restrict__ e16,
                                                   const int* __restrict__ row_off,
                                                   _Float16* __restrict__ esum16) {
    int d = blockIdx.x * 4 + (threadIdx.x >> 6);
    int lane = threadIdx.x & 63;
    if (d >= N_) return;
    int beg = row_off[d], end = row_off[d + 1];
    float s = 0.f;
    for (int i = beg; i < end; ++i) s += (float)e16[(size_t)i * ED_ + lane];
    esum16[(size_t)d * ED_ + lane] = (_Float16)s;
}

// ---------------- phase B: wave-per-dst softmax + aggregation + silu/LN ------
__global__ __launch_bounds__(256) void gat_agg4(const _Float16* __restrict__ xlr16,
                                                const _Float16* __restrict__ loopW16,
                                                const int* __restrict__ row_off,
                                                const int* __restrict__ srcp,
                                                const float* __restrict__ exlog,
                                                const float* __restrict__ att,
                                                const float* __restrict__ bias,
                                                const float* __restrict__ gs,
                                                const float* __restrict__ gb,
                                                _Float16* __restrict__ hn16) {
    int t = threadIdx.x;
    int w = t >> 6, lane = t & 63;
    int d = blockIdx.x * 4 + w;
    if (d >= N_) return;
    int beg = row_off[d], end = row_off[d + 1];
    int deg = end - beg;
    int hh = lane >> 4;
    float4 av = *(const float4*)&att[lane * 4];
    f16x4 xld_h = *(const f16x4*)&xlr16[(size_t)d * 512 + lane * 4];
    f16x4 xrd_h = *(const f16x4*)&xlr16[(size_t)d * 512 + 256 + lane * 4];
    float xld[4], xrd[4];
#pragma unroll
    for (int j = 0; j < 4; ++j) { xld[j] = (float)xld_h[j]; xrd[j] = (float)xrd_h[j]; }
    float den = 0.f;
    float out[4] = {0.f, 0.f, 0.f, 0.f};
    int i = beg;
    for (; i + 4 <= end; i += 4) {
        int s0 = srcp[i], s1 = srcp[i + 1], s2 = srcp[i + 2], s3 = srcp[i + 3];
        float ex0 = exlog[(size_t)i * H_ + hh];
        float ex1 = exlog[(size_t)(i + 1) * H_ + hh];
        float ex2 = exlog[(size_t)(i + 2) * H_ + hh];
        float ex3 = exlog[(size_t)(i + 3) * H_ + hh];
        f16x4 x0 = *(const f16x4*)&xlr16[(size_t)s0 * 512 + lane * 4];
        f16x4 x1 = *(const f16x4*)&xlr16[(size_t)s1 * 512 + lane * 4];
        f16x4 x2 = *(const f16x4*)&xlr16[(size_t)s2 * 512 + lane * 4];
        f16x4 x3 = *(const f16x4*)&xlr16[(size_t)s3 * 512 + lane * 4];
        den += (ex0 + ex1) + (ex2 + ex3);
#pragma unroll
        for (int j = 0; j < 4; ++j)
            out[j] += ex0 * (float)x0[j] + ex1 * (float)x1[j] +
                      ex2 * (float)x2[j] + ex3 * (float)x3[j];
    }
    for (; i < end; ++i) {
        int s0 = srcp[i];
        float ex0 = exlog[(size_t)i * H_ + hh];
        f16x4 x0 = *(const f16x4*)&xlr16[(size_t)s0 * 512 + lane * 4];
        den += ex0;
#pragma unroll
        for (int j = 0; j < 4; ++j) out[j] += ex0 * (float)x0[j];
    }
    // self loop
    f16x4 lw4 = *(const f16x4*)&loopW16[(size_t)d * D_ + lane * 4];
    float idg = (deg > 0) ? 1.f / (float)deg : 0.f;
    {
        float v = 0.f;
        float avv[4] = {av.x, av.y, av.z, av.w};
#pragma unroll
        for (int j = 0; j < 4; ++j) {
            float m = xld[j] + xrd[j] + (float)lw4[j] * idg;
            m = fmaxf(m, 0.2f * m);
            v += m * avv[j];
        }
        v += __shfl_xor(v, 1); v += __shfl_xor(v, 2);
        v += __shfl_xor(v, 4); v += __shfl_xor(v, 8);  // 16-lane head group
        float eself = expf(v);
        den += eself;
#pragma unroll
        for (int j = 0; j < 4; ++j) out[j] += eself * xld[j];
    }
    float inv = 1.f / (den + 1e-16f);
    float4 b4 = *(const float4*)&bias[lane * 4];
    float bv[4] = {b4.x, b4.y, b4.z, b4.w};
    float v4[4], s = 0.f;
#pragma unroll
    for (int j = 0; j < 4; ++j) {
        float v = out[j] * inv + bv[j];
        v = v / (1.f + expf(-v));
        v4[j] = v;
        s += v;
    }
#pragma unroll
    for (int o = 32; o; o >>= 1) s += __shfl_xor(s, o);
    float mu = s * (1.f / 256.f);
    float q = 0.f;
#pragma unroll
    for (int j = 0; j < 4; ++j) { float dv = v4[j] - mu; q += dv * dv; }
#pragma unroll
    for (int o = 32; o; o >>= 1) q += __shfl_xor(q, o);
    float rs = rsqrtf(q * (1.f / 256.f) + 1e-5f);
    float4 g4 = *(const float4*)&gs[lane * 4];
    float4 gb4 = *(const float4*)&gb[lane * 4];
    f16x4 o4;
    float gsv[4] = {g4.x, g4.y, g4.z, g4.w};
    float gbv[4] = {gb4.x, gb4.y, gb4.z, gb4.w};
#pragma unroll
    for (int j = 0; j < 4; ++j) o4[j] = (_Float16)((v4[j] - mu) * rs * gsv[j] + gbv[j]);
    *(f16x4*)&hn16[(size_t)d * D_ + lane * 4] = o4;
}

// ---------------- fused edge MLP (permuted eW3; vectorized gathers/stores) ----
__global__ __launch_bounds__(256) void edge_mlp_mfma(_Float16* __restrict__ e16,
                                                     const _Float16* __restrict__ ew3Tp16,
                                                     const _Float16* __restrict__ hsd16,
                                                     const int* __restrict__ srcp,
                                                     const int* __restrict__ dstp,
                                                     const float* __restrict__ eb,
                                                     const float* __restrict__ gs,
                                                     const float* __restrict__ gb) {
    int t = threadIdx.x;
    int w = t >> 6, l = t & 63;
    int bm = blockIdx.x * 64;
    int cgrp = l & 15;
    int arow = bm + w * 16 + cgrp;
    int koff = (l >> 4) * 8;
    const _Float16* Ap = e16 + (size_t)arow * ED_ + koff;
    f16x8 a0 = *(const f16x8*)(Ap);
    f16x8 a1 = *(const f16x8*)(Ap + 32);
    f32x4 acc[4];
#pragma unroll
    for (int nt = 0; nt < 4; ++nt) {
        const _Float16* bp = ew3Tp16 + (size_t)(nt * 16 + cgrp) * 64 + koff;
        f16x8 b0 = *(const f16x8*)(bp);
        f16x8 b1 = *(const f16x8*)(bp + 32);
        f32x4 z = {};
        z = __builtin_amdgcn_mfma_f32_16x16x32_f16(a0, b0, z, 0, 0, 0);
        z = __builtin_amdgcn_mfma_f32_16x16x32_f16(a1, b1, z, 0, 0, 0);
        acc[nt] = z;
    }
    f32x4 ebv = *(const f32x4*)&eb[cgrp * 4];
    f32x4 gsv = *(const f32x4*)&gs[cgrp * 4];
    f32x4 gbv = *(const f32x4*)&gb[cgrp * 4];
    int rbase = bm + w * 16 + (l >> 4) * 4;
#pragma unroll
    for (int r = 0; r < 4; ++r) {
        int row = rbase + r;
        int s = srcp[row], d = dstp[row];
        f16x4 hs = *(const f16x4*)&hsd16[(size_t)s * 128 + cgrp * 4];
        f16x4 hd = *(const f16x4*)&hsd16[(size_t)d * 128 + 64 + cgrp * 4];
        float v4[4], ss = 0.f;
#pragma unroll
        for (int nt = 0; nt < 4; ++nt) {
            float vv = acc[nt][r] + (float)hs[nt] + (float)hd[nt] + ebv[nt];
            vv = vv / (1.f + expf(-vv));
            v4[nt] = vv;
            ss += vv;
        }
        ss += __shfl_xor(ss, 1); ss += __shfl_xor(ss, 2);
        ss += __shfl_xor(ss, 4); ss += __shfl_xor(ss, 8);
        float mu = ss * (1.f / 64.f);
        float q = 0.f;
#pragma unroll
        for (int nt = 0; nt < 4; ++nt) { float dv = v4[nt] - mu; q += dv * dv; }
        q += __shfl_xor(q, 1); q += __shfl_xor(q, 2);
        q += __shfl_xor(q, 4); q += __shfl_xor(q, 8);
        float rsd = rsqrtf(q * (1.f / 64.f) + 1e-5f);
        f16x4 o4;
#pragma unroll
        for (int nt = 0; nt < 4; ++nt)
            o4[nt] = (_Float16)((v4[nt] - mu) * rsd * gsv[nt] + gbv[nt]);
        *(f16x4*)&e16[(size_t)row * ED_ + cgrp * 4] = o4;
    }
}

// ---------------- node silu + LN (final JK output; f32 + f16 outs) ----------
__global__ __launch_bounds__(256) void node_silu_ln(const float* __restrict__ inp,
                                                    const float* __restrict__ gs,
                                                    const float* __restrict__ gb,
                                                    float* __restrict__ outp,
                                                    _Float16* __restrict__ outp16) {
    int n = blockIdx.x, t = threadIdx.x;
    float v = inp[(size_t)n * D_ + t];
    v = v / (1.f + expf(-v));
    __shared__ float red[4];
    float s = v;
#pragma unroll
    for (int o = 32; o; o >>= 1) s += __shfl_xor(s, o);
    if ((t & 63) == 0) red[t >> 6] = s;
    __syncthreads();
    float mu = (red[0] + red[1] + red[2] + red[3]) * (1.f / 256.f);
    __syncthreads();
    float dv = v - mu;
    float q = dv * dv;
#pragma unroll
    for (int o = 32; o; o >>= 1) q += __shfl_xor(q, o);
    if ((t & 63) == 0) red[t >> 6] = q;
    __syncthreads();
    float var = (red[0] + red[1] + red[2] + red[3]) * (1.f / 256.f);
    float r = dv * rsqrtf(var + 1e-5f) * gs[t] + gb[t];
    outp[(size_t)n * D_ + t] = r;
    outp16[(size_t)n * D_ + t] = (_Float16)r;
}

// ---------------- gate lite: silu(hid)·gW2 reduce (no atomics) ---------------
__global__ __launch_bounds__(256) void gate_lite(const _Float16* __restrict__ hid16,
                                                 const float* __restrict__ gW2,
                                                 const float* __restrict__ gb2,
                                                 float* __restrict__ g) {
    int t = threadIdx.x;
    int w = t >> 6, lane = t & 63;
    int n = blockIdx.x * 4 + w;
    if (n >= N_) return;
    f16x2 h2 = *(const f16x2*)&hid16[(size_t)n * 128 + lane * 2];
    float h0 = (float)h2[0], h1 = (float)h2[1];
    float w0 = gW2[lane * 2], w1 = gW2[lane * 2 + 1];
    float s0 = h0 / (1.f + expf(-h0));
    float s1 = h1 / (1.f + expf(-h1));
    float v = s0 * w0 + s1 * w1;
#pragma unroll
    for (int o = 32; o; o >>= 1) v += __shfl_xor(v, o);
    if (lane == 0) g[n] = v + gb2[0];
}

// ---------------- fused per-graph pool: denom + weighted sum + head ----------
__global__ __launch_bounds__(256) void graphpool(const float* __restrict__ hfin,
                                                 const float* __restrict__ g,
                                                 const int* __restrict__ goff,
                                                 const float* __restrict__ hW,
                                                 const float* __restrict__ hb,
                                                 float* __restrict__ out) {
    int b = blockIdx.x, t = threadIdx.x;
    int w = t >> 6, lane = t & 63;
    int beg = goff[b], end = goff[b + 1];
    __shared__ float red[4];
    __shared__ float wls[256];
    float den = 0.f;
    for (int n = beg + t; n < end; n += 256) den += expf(g[n]);
#pragma unroll
    for (int o = 32; o; o >>= 1) den += __shfl_xor(den, o);
    if (lane == 0) red[w] = den;
    __syncthreads();
    float dtot = red[0] + red[1] + red[2] + red[3];
    float inv = 1.f / (dtot + 1e-16f);
    float acc = 0.f;
    for (int c0 = beg; c0 < end; c0 += 256) {
        int nn = min(256, end - c0);
        __syncthreads();
        if (t < nn) wls[t] = expf(g[c0 + t]) * inv;
        __syncthreads();
        for (int j = 0; j < nn; ++j)
            acc += wls[j] * hfin[(size_t)(c0 + j) * D_ + t];
    }
    float v = acc * hW[t];
#pragma unroll
    for (int o = 32; o; o >>= 1) v += __shfl_xor(v, o);
    __syncthreads();
    if (lane == 0) red[w] = v;
    __syncthreads();
    if (t == 0) out[b] = red[0] + red[1] + red[2] + red[3] + hb[0];
}

// ---------------- host launch ----------------
extern "C" void kernel_launch(void* const* d_in, const int* in_sizes, int n_in,
                              void* d_out, int out_size, void* d_ws, size_t ws_size,
                              hipStream_t stream) {
    const float* x     = (const float*)d_in[0];
    const int*   eidx  = (const int*)d_in[1];
    const float* eattr = (const float*)d_in[2];
    const int*   batch = (const int*)d_in[3];
    const float* atomW = (const float*)d_in[4];
    const float* atomB = (const float*)d_in[5];
    const float* bondW = (const float*)d_in[6];
    const float* bondB = (const float*)d_in[7];
    const float* Wl    = (const float*)d_in[8];
    const float* bl    = (const float*)d_in[9];
    const float* Wr    = (const float*)d_in[10];
    const float* br    = (const float*)d_in[11];
    const float* We    = (const float*)d_in[12];
    const float* att   = (const float*)d_in[13];
    const float* bias  = (const float*)d_in[14];
    const float* ln1s  = (const float*)d_in[15];
    const float* ln1b  = (const float*)d_in[16];
    const float* eW    = (const float*)d_in[17];
    const float* eb    = (const float*)d_in[18];
    const float* ln2s  = (const float*)d_in[19];
    const float* ln2b  = (const float*)d_in[20];
    const float* jkW   = (const float*)d_in[21];
    const float* jkb   = (const float*)d_in[22];
    const float* ln3s  = (const float*)d_in[23];
    const float* ln3b  = (const float*)d_in[24];
    const float* gW1   = (const float*)d_in[25];
    const float* gb1   = (const float*)d_in[26];
    const float* gW2   = (const float*)d_in[27];
    const float* gb2   = (const float*)d_in[28];
    const float* hW    = (const float*)d_in[29];
    const float* hb    = (const float*)d_in[30];

    const int* src = eidx;
    const int* dst = eidx + E_;

    // ---- workspace layout ----
    char* wp = (char*)d_ws;
    auto take = [&](size_t bytes) {
        char* p = wp;
        wp += (bytes + 255) & ~(size_t)255;
        return (void*)p;
    };
    _Float16*  e16     = (_Float16*)take((size_t)E_ * ED_ * 2);  // 40.96 MB, CSR-permuted
    _Float16*  xlr16   = (_Float16*)take((size_t)N_ * 512 * 2);  // 20.48 MB (xl|xr packed)
    float*     jkacc   = (float*)take((size_t)N_ * D_ * 4);      // 20.48 MB
    _Float16*  loopW16 = (_Float16*)take((size_t)N_ * D_ * 2);   // 10.24 MB
    float*     hfin    = (float*)take((size_t)N_ * D_ * 4);      // 20.48 MB
    _Float16*  hfin16  = (_Float16*)take((size_t)N_ * D_ * 2);   // 10.24 MB
    _Float16*  hid16   = (_Float16*)take((size_t)N_ * 128 * 2);  // 5.12 MB
    _Float16*  h16A    = (_Float16*)take((size_t)N_ * D_ * 2);   // 10.24 MB
    _Float16*  h16B    = (_Float16*)take((size_t)N_ * D_ * 2);   // 10.24 MB
    _Float16*  hsd16   = (_Float16*)take((size_t)N_ * 128 * 2);  // 5.12 MB (hsW|hdW packed)
    float*     exlog   = (float*)take((size_t)E_ * H_ * 4);      // 5.12 MB
    _Float16*  esum16  = (_Float16*)take((size_t)N_ * ED_ * 2);  // 2.56 MB
    _Float16*  wlrT16  = (_Float16*)take((size_t)L_ * 512 * D_ * 2);
    _Float16*  weT16   = (_Float16*)take((size_t)L_ * ED_ * D_ * 2);
    _Float16*  weTp16  = (_Float16*)take((size_t)L_ * ED_ * D_ * 2);  // permuted (edge_logits)
    _Float16*  ewsdT16 = (_Float16*)take((size_t)L_ * 128 * D_ * 2);
    _Float16*  ew3Tp16 = (_Float16*)take((size_t)L_ * ED_ * ED_ * 2); // permuted (edge_mlp)
    _Float16*  jkwT16  = (_Float16*)take((size_t)L_ * D_ * D_ * 2);
    _Float16*  g1T16   = (_Float16*)take((size_t)D_ * 128 * 2);
    float*     blr     = (float*)take((size_t)L_ * 512 * 4);
    int*   deg_i   = (int*)take((size_t)N_ * 4);
    int*   fill    = (int*)take((size_t)N_ * 4);
    int*   row_off = (int*)take((size_t)(N_ + 1) * 4);
    int*   goff    = (int*)take((size_t)(G_ + 1) * 4);
    int*   perm    = (int*)take((size_t)E_ * 4);
    int*   srcp    = (int*)take((size_t)E_ * 4);
    int*   dstp    = (int*)take((size_t)E_ * 4);
    float* g       = (float*)take((size_t)N_ * 4);

    // ---- weight pre-pack (f32 -> transposed f16) ----
    auto pack = [&](const float* W, _Float16* WT, int K, int Nn) {
        pack_wT<<<(K * Nn + 255) / 256, 256, 0, stream>>>(W, WT, K, Nn);
    };
    for (int l = 0; l < L_; ++l) {
        pack(Wl + (size_t)l * D_ * D_, wlrT16 + (size_t)l * 512 * D_, D_, D_);
        pack(Wr + (size_t)l * D_ * D_, wlrT16 + (size_t)l * 512 * D_ + (size_t)D_ * D_, D_, D_);
        pack(We + (size_t)l * ED_ * D_, weT16 + (size_t)l * ED_ * D_, ED_, D_);
        pack_wT_perm<<<(64 * 256 + 255) / 256, 256, 0, stream>>>(
            We + (size_t)l * ED_ * D_, weTp16 + (size_t)l * ED_ * D_);
        const float* eW_l = eW + (size_t)l * (2 * D_ + ED_) * ED_;
        pack(eW_l,                        ewsdT16 + (size_t)l * 128 * D_, D_, ED_);
        pack(eW_l + (size_t)D_ * ED_,     ewsdT16 + (size_t)l * 128 * D_ + (size_t)ED_ * D_, D_, ED_);
        pack_wT_perm64<<<(64 * 64 + 255) / 256, 256, 0, stream>>>(
            eW_l + (size_t)2 * D_ * ED_, ew3Tp16 + (size_t)l * ED_ * ED_);
        pack(jkW + (size_t)l * D_ * D_,   jkwT16 + (size_t)l * D_ * D_, D_, D_);
        hipMemcpyAsync(blr + (size_t)l * 512,       bl + (size_t)l * D_, D_ * 4,
                       hipMemcpyDeviceToDevice, stream);
        hipMemcpyAsync(blr + (size_t)l * 512 + D_,  br + (size_t)l * D_, D_ * 4,
                       hipMemcpyDeviceToDevice, stream);
    }
    pack(gW1, g1T16, D_, 128);

    // ---- CSR build + graph boundaries ----
    hipMemsetAsync(deg_i, 0, (size_t)N_ * 4, stream);
    hipMemsetAsync(fill, 0, (size_t)N_ * 4, stream);
    count_kernel<<<(E_ + 255) / 256, 256, 0, stream>>>(dst, deg_i);
    scan_kernel<<<1, 1024, 0, stream>>>(deg_i, row_off);
    fill_kernel<<<(E_ + 255) / 256, 256, 0, stream>>>(src, dst, row_off, fill,
                                                      perm, srcp, dstp);
    goff_kernel<<<1, 256, 0, stream>>>(batch, goff);

    // encoders
    atom_enc<<<N_, 256, 0, stream>>>(x, atomW, atomB, h16A);
    bond_enc_perm<<<(E_ * ED_ + 255) / 256, 256, 0, stream>>>(eattr, bondW, bondB,
                                                              perm, e16);

    const int MB = (N_ + 63) / 64;  // 313
    const _Float16* h16_prev = h16A;
    for (int l = 0; l < L_; ++l) {
        const float* att_l = att + (size_t)l * H_ * C_;
        const float* bias_l = bias + (size_t)l * D_;
        const float* ln1s_l = ln1s + (size_t)l * D_;
        const float* ln1b_l = ln1b + (size_t)l * D_;
        const float* eb_l = eb + (size_t)l * ED_;
        const float* ln2s_l = ln2s + (size_t)l * ED_;
        const float* ln2b_l = ln2b + (size_t)l * ED_;
        const _Float16* weT_l = weT16 + (size_t)l * ED_ * D_;
        _Float16* hn16_l = (l & 1) ? h16A : h16B;

        // xl|xr projection (single MFMA GEMM, N=512, f16 out with combined bias)
        mfma_gemm16<<<dim3(MB, 8), 256, 0, stream>>>(h16_prev,
                                                     wlrT16 + (size_t)l * 512 * D_,
                                                     blr + (size_t)l * 512,
                                                     xlr16, N_, D_, 512);

        // self-loop: esum16 @ We -> loopW16 (f16)
        esum_kernel<<<(N_ + 3) / 4, 256, 0, stream>>>(e16, row_off, esum16);
        mfma_gemm16<<<dim3(MB, 4), 256, 0, stream>>>(esum16, weT_l, nullptr,
                                                     loopW16, N_, ED_, D_);

        // phase A: fused MFMA edge logits (no-LDS, permuted weights)
        edge_logits_mfma<<<E_ / 64, 256, 0, stream>>>(e16,
                                                      weTp16 + (size_t)l * ED_ * D_,
                                                      xlr16, srcp, dstp, att_l, exlog);

        // phase B: wave-per-dst softmax + aggregation + silu/LN -> hn16
        gat_agg4<<<(N_ + 3) / 4, 256, 0, stream>>>(xlr16, loopW16, row_off, srcp,
                                                   exlog, att_l, bias_l,
                                                   ln1s_l, ln1b_l, hn16_l);

        // edge MLP: hsd16 = hn@[eWs|eWd] (one GEMM), then fused MFMA+LN in-place
        mfma_gemm16<<<dim3(MB, 2), 256, 0, stream>>>(hn16_l,
                                                     ewsdT16 + (size_t)l * 128 * D_,
                                                     nullptr, hsd16, N_, D_, 128);
        edge_mlp_mfma<<<E_ / 64, 256, 0, stream>>>(e16, ew3Tp16 + (size_t)l * ED_ * ED_,
                                                   hsd16, srcp, dstp,
                                                   eb_l, ln2s_l, ln2b_l);

        // incremental JK: jkacc (+)= hn @ jkW_l (f32 accum)
        mfma_gemm<<<dim3(MB, 4), 256, 0, stream>>>(hn16_l, jkwT16 + (size_t)l * D_ * D_,
                                                   (l == 0) ? jkb : nullptr,
                                                   jkacc, N_, D_, D_, (l == 0) ? 0 : 1);

        h16_prev = hn16_l;
    }

    node_silu_ln<<<N_, 256, 0, stream>>>(jkacc, ln3s, ln3b, hfin, hfin16);

    // gate MLP (MFMA, f16 hid) -> per-node logit -> fused per-graph pool + head
    mfma_gemm16<<<dim3(MB, 2), 256, 0, stream>>>(hfin16, g1T16, gb1, hid16, N_, D_, 128);
    gate_lite<<<(N_ + 3) / 4, 256, 0, stream>>>(hid16, gW2, gb2, g);
    graphpool<<<G_, 256, 0, stream>>>(hfin, g, goff, hW, hb, (float*)d_out);
}